// Round 4
// baseline (153.298 us; speedup 1.0000x reference)
//
#include <hip/hip_runtime.h>

#define NPTS 65536
#define MPTS 65536
#define FSTR 88            // featB row stride in shorts (176 B, 16B-aligned, 44 dw -> 12*lr mod 32 bank spread)

typedef __attribute__((ext_vector_type(8))) short bf16x8;
typedef __attribute__((ext_vector_type(4))) float f32x4;

__device__ __forceinline__ float bflo(unsigned int u){ union{unsigned int i; float f;} v; v.i = u<<16; return v.f; }
__device__ __forceinline__ float bfhi(unsigned int u){ union{unsigned int i; float f;} v; v.i = u & 0xffff0000u; return v.f; }
__device__ __forceinline__ unsigned short f2bf(float f){
  union{float f; unsigned int i;} v; v.f=f;
  unsigned int r = v.i + 0x7fffu + ((v.i>>16)&1u);  // RNE
  return (unsigned short)(r>>16);
}

// ---- pack x[64][N] + pos[3][N] -> P2[N][72] bf16; blocks 0..6 also pack weights ----
__global__ __launch_bounds__(256) void pack_all(
    const float* __restrict__ x, const float* __restrict__ pos,
    const float* __restrict__ W1, const float* __restrict__ W2,
    unsigned short* __restrict__ P2,
    unsigned short* __restrict__ W1F, unsigned short* __restrict__ W2F) {
  __shared__ unsigned int tile[64 * 37];   // 64 points x 36 dwords (+1 pad: banks 5p mod 32)
  const int t = threadIdx.x;
  const int n0 = blockIdx.x * 64;
  const int p = t & 63, cq = t >> 6;
  const int n = n0 + p;
  #pragma unroll
  for (int jj = 0; jj < 8; ++jj) {         // 16 channels per thread, paired -> dword writes
    const int c = cq * 16 + 2 * jj;
    const unsigned int lo = f2bf(x[(size_t)c * NPTS + n]);
    const unsigned int hi = f2bf(x[(size_t)(c + 1) * NPTS + n]);
    tile[p * 37 + cq * 8 + jj] = lo | (hi << 16);
  }
  if (cq == 0) {                           // wave 0: pos channels + zero pad
    const unsigned int a = f2bf(pos[n]);
    const unsigned int b = f2bf(pos[NPTS + n]);
    const unsigned int cc = f2bf(pos[2 * NPTS + n]);
    tile[p * 37 + 32] = a | (b << 16);
    tile[p * 37 + 33] = cc;                // col 67 zero in hi
    tile[p * 37 + 34] = 0u;
    tile[p * 37 + 35] = 0u;
  }
  __syncthreads();
  unsigned int* Pd = (unsigned int*)(P2 + (size_t)n0 * 72);
  #pragma unroll
  for (int i = 0; i < 9; ++i) {            // 2304 dwords, coalesced out
    const int u = t + i * 256;
    const int nl = u / 36, d = u - nl * 36;
    Pd[u] = tile[nl * 37 + d];
  }
  // ---- weight fragment images (first 7 blocks only) ----
  if (blockIdx.x < 7) {
    const int f = blockIdx.x * 256 + t;
    if (f < 768) {
      const int kt = f >> 8, rem = f & 255, nt = rem >> 6, lane = rem & 63;
      const int h = nt*16 + (lane & 15);
      const int c0 = kt*32 + (lane >> 4) * 8;
      #pragma unroll
      for (int j = 0; j < 8; ++j) {
        const int c = c0 + j;
        W1F[f*8 + j] = (c < 67) ? f2bf(W1[h*67 + c]) : (unsigned short)0;
      }
    } else if (f < 1792) {
      const int g = f - 768;
      const int kt = g >> 9, rem = g & 511, ot = rem >> 6, lane = rem & 63;
      const int o = ot*16 + (lane & 15);
      const int h0 = kt*32 + (lane >> 4) * 8;
      #pragma unroll
      for (int j = 0; j < 8; ++j) W2F[g*8 + j] = f2bf(W2[o*64 + h0 + j]);
    }
  }
}

#define MFMA16(a,b,c) __builtin_amdgcn_mfma_f32_16x16x32_bf16((a),(b),(c),0,0,0)

// ---- fused gather -> MLP1(relu) -> MLP2 -> max over K; waves independent, 1 barrier ----
__global__ __launch_bounds__(256, 3) void pointnet_mfma(
    const unsigned short* __restrict__ P2,   // [N][72] bf16
    const float* __restrict__ sup,           // [3][M] fp32
    const unsigned short* __restrict__ W1F,
    const float* __restrict__ b1,
    const unsigned short* __restrict__ W2F,
    const float* __restrict__ b2,
    const int* __restrict__ indices,         // [M][16]
    float* __restrict__ out) {               // [128][M] fp32
  __shared__ __align__(16) char smem[53248];
  unsigned short* featB = (unsigned short*)smem;   // [256][88] bf16, cols 0..71 valid
  unsigned short* hlds  = (unsigned short*)smem;   // overlay [256][88], cols 0..63 (post-stage1)
  float* smax = (float*)(smem + 45056);            // [16][128] fp32

  const int t = threadIdx.x;
  const int m0 = blockIdx.x * 16;
  const int lane = t & 63, w = t >> 6, quad = lane >> 4, lr = lane & 15;

  // ---- gather: thread t owns point t (wave-private LDS rows) ----
  {
    const int idx = indices[m0*16 + t];
    const uint4* src = (const uint4*)(P2 + (size_t)idx * 72);
    uint4 u[9];
    #pragma unroll
    for (int i = 0; i < 9; ++i) u[i] = src[i];
    const int mm = m0 + (t >> 4);
    const float s0 = sup[mm], s1 = sup[MPTS + mm], s2 = sup[2*MPTS + mm];
    const float p0 = bflo(u[8].x), p1 = bfhi(u[8].x), p2 = bflo(u[8].y);
    u[8].x = (unsigned int)f2bf(p0 - s0) | ((unsigned int)f2bf(p1 - s1) << 16);
    u[8].y = (unsigned int)f2bf(p2 - s2);   // col 67 = 0
    u[8].z = 0u; u[8].w = 0u;               // cols 68..71 = 0
    uint4* dst = (uint4*)(featB + t * FSTR);
    #pragma unroll
    for (int i = 0; i < 9; ++i) dst[i] = u[i];
  }

  // W1 fragments + bias (L2-hot) — overlaps the gather's vmcnt
  bf16x8 w1f[3][4];
  #pragma unroll
  for (int kt = 0; kt < 3; ++kt)
    #pragma unroll
    for (int nt = 0; nt < 4; ++nt)
      w1f[kt][nt] = ((const bf16x8*)W1F)[(kt*4 + nt)*64 + lane];
  float b1s[4];
  #pragma unroll
  for (int nt = 0; nt < 4; ++nt) b1s[nt] = b1[nt*16 + lr];

  // ---- stage 1 (wave-local; compiler lgkmcnt orders LDS) ----
  const f32x4 fz = {0.f, 0.f, 0.f, 0.f};
  f32x4 acc[4][4];
  #pragma unroll
  for (int pt = 0; pt < 4; ++pt)
    #pragma unroll
    for (int nt = 0; nt < 4; ++nt) acc[pt][nt] = fz;
  #pragma unroll
  for (int kt = 0; kt < 2; ++kt) {         // full K=64 over features
    bf16x8 af[4];
    #pragma unroll
    for (int pt = 0; pt < 4; ++pt)
      af[pt] = *(const bf16x8*)&featB[(w*64 + pt*16 + lr)*FSTR + kt*32 + quad*8];
    #pragma unroll
    for (int pt = 0; pt < 4; ++pt)
      #pragma unroll
      for (int nt = 0; nt < 4; ++nt)
        acc[pt][nt] = MFMA16(af[pt], w1f[kt][nt], acc[pt][nt]);
  }
  {                                        // kt=2: only k=64..71 nonzero -> broadcast + select
    const bf16x8 zv = {0,0,0,0,0,0,0,0};
    bf16x8 af[4];
    #pragma unroll
    for (int pt = 0; pt < 4; ++pt) {
      const bf16x8 v = *(const bf16x8*)&featB[(w*64 + pt*16 + lr)*FSTR + 64];
      af[pt] = (quad == 0) ? v : zv;
    }
    #pragma unroll
    for (int pt = 0; pt < 4; ++pt)
      #pragma unroll
      for (int nt = 0; nt < 4; ++nt)
        acc[pt][nt] = MFMA16(af[pt], w1f[2][nt], acc[pt][nt]);
  }

  // relu(bias) -> hlds (wave-private rows; program order vs featB reads)
  #pragma unroll
  for (int pt = 0; pt < 4; ++pt)
    #pragma unroll
    for (int nt = 0; nt < 4; ++nt) {
      const int h = nt*16 + lr;
      const int pbase = w*64 + pt*16 + quad*4;
      #pragma unroll
      for (int r = 0; r < 4; ++r)
        hlds[(pbase + r)*FSTR + h] = f2bf(fmaxf(acc[pt][nt][r] + b1s[nt], 0.f));
    }

  // ---- stage 2 + per-wave k-max ----
  #pragma unroll
  for (int oh = 0; oh < 2; ++oh) {
    bf16x8 w2f[2][4];
    #pragma unroll
    for (int kt = 0; kt < 2; ++kt)
      #pragma unroll
      for (int ot = 0; ot < 4; ++ot)
        w2f[kt][ot] = ((const bf16x8*)W2F)[(kt*8 + oh*4 + ot)*64 + lane];
    f32x4 a2[4][4];
    #pragma unroll
    for (int pt = 0; pt < 4; ++pt)
      #pragma unroll
      for (int ot = 0; ot < 4; ++ot) a2[pt][ot] = fz;
    #pragma unroll
    for (int kt = 0; kt < 2; ++kt) {
      bf16x8 ah[4];
      #pragma unroll
      for (int pt = 0; pt < 4; ++pt)
        ah[pt] = *(const bf16x8*)&hlds[(w*64 + pt*16 + lr)*FSTR + kt*32 + quad*8];
      #pragma unroll
      for (int pt = 0; pt < 4; ++pt)
        #pragma unroll
        for (int ot = 0; ot < 4; ++ot)
          a2[pt][ot] = MFMA16(ah[pt], w2f[kt][ot], a2[pt][ot]);
    }
    #pragma unroll
    for (int pt = 0; pt < 4; ++pt)
      #pragma unroll
      for (int ot = 0; ot < 4; ++ot) {
        f32x4 v4 = a2[pt][ot];
        float v = fmaxf(fmaxf(v4[0], v4[1]), fmaxf(v4[2], v4[3]));
        v = fmaxf(v, __shfl_xor(v, 16));
        v = fmaxf(v, __shfl_xor(v, 32));
        if (quad == 0) smax[(w*4 + pt)*128 + oh*64 + ot*16 + lr] = v;
      }
  }
  __syncthreads();   // the only block-wide barrier

  // ---- coalesced store: out[o][m0..m0+15] (block-exclusive 64B lines) ----
  #pragma unroll
  for (int i = 0; i < 2; ++i) {
    const int u = t + i*256;
    const int o = u >> 2, mg = u & 3;
    const float bb = b2[o];
    float4 val;
    val.x = smax[(mg*4 + 0)*128 + o] + bb;
    val.y = smax[(mg*4 + 1)*128 + o] + bb;
    val.z = smax[(mg*4 + 2)*128 + o] + bb;
    val.w = smax[(mg*4 + 3)*128 + o] + bb;
    *(float4*)(out + (size_t)o * MPTS + m0 + mg*4) = val;
  }
}

// ---- fallback (ws too small): direct fp32 kernel, known-correct ----
__global__ __launch_bounds__(256) void pointnet_fallback(
    const float* __restrict__ x, const float* __restrict__ pos,
    const float* __restrict__ sup,
    const float* __restrict__ W1, const float* __restrict__ b1,
    const float* __restrict__ W2, const float* __restrict__ b2,
    const int* __restrict__ indices, float* __restrict__ out) {
  __shared__ float sfeat[16][68];
  __shared__ float shid[16][64];
  __shared__ float smax[4][128];
  __shared__ int sidx[16];
  const int t = threadIdx.x;
  const int m = blockIdx.x;
  if (t < 16) sidx[t] = indices[m*16 + t];
  const float sup0 = sup[m], sup1 = sup[MPTS + m], sup2 = sup[2*MPTS + m];
  __syncthreads();
  for (int u = t; u < 16*17; u += 256) {
    const int k = u / 17, c4 = (u - k*17) * 4;
    const int idx = sidx[k];
    float4 w;
    if (c4 < 64) {
      w.x = x[(size_t)(c4+0)*NPTS + idx]; w.y = x[(size_t)(c4+1)*NPTS + idx];
      w.z = x[(size_t)(c4+2)*NPTS + idx]; w.w = x[(size_t)(c4+3)*NPTS + idx];
    } else {
      w.x = pos[idx] - sup0; w.y = pos[NPTS + idx] - sup1;
      w.z = pos[2*NPTS + idx] - sup2; w.w = 0.f;
    }
    *(float4*)&sfeat[k][c4] = w;
  }
  const int h = t & 63, kg = t >> 6;
  float w1r[68];
  #pragma unroll
  for (int c = 0; c < 67; ++c) w1r[c] = W1[h*67 + c];
  w1r[67] = 0.f;
  const float bias1 = b1[h];
  __syncthreads();
  #pragma unroll
  for (int j = 0; j < 4; ++j) {
    const int k = kg*4 + j;
    float a = bias1;
    const float4* rr = (const float4*)sfeat[k];
    #pragma unroll
    for (int q = 0; q < 17; ++q) {
      const float4 v = rr[q];
      a += w1r[q*4+0]*v.x + w1r[q*4+1]*v.y + w1r[q*4+2]*v.z + w1r[q*4+3]*v.w;
    }
    shid[k][h] = fmaxf(a, 0.f);
  }
  const int ow = t & 63;
  float w2a[64], w2b[64];
  #pragma unroll
  for (int hh = 0; hh < 64; ++hh) { w2a[hh] = W2[ow*64 + hh]; w2b[hh] = W2[(ow+64)*64 + hh]; }
  __syncthreads();
  float mxa = -3.0e38f, mxb = -3.0e38f;
  #pragma unroll
  for (int j = 0; j < 4; ++j) {
    const int k = kg*4 + j;
    const float4* hr = (const float4*)shid[k];
    float pa = 0.f, pb = 0.f;
    #pragma unroll
    for (int q = 0; q < 16; ++q) {
      const float4 v = hr[q];
      pa += w2a[q*4+0]*v.x + w2a[q*4+1]*v.y + w2a[q*4+2]*v.z + w2a[q*4+3]*v.w;
      pb += w2b[q*4+0]*v.x + w2b[q*4+1]*v.y + w2b[q*4+2]*v.z + w2b[q*4+3]*v.w;
    }
    mxa = fmaxf(mxa, pa); mxb = fmaxf(mxb, pb);
  }
  smax[kg][ow] = mxa; smax[kg][64 + ow] = mxb;
  __syncthreads();
  if (t < 128) {
    out[(size_t)t * MPTS + m] =
        fmaxf(fmaxf(smax[0][t], smax[1][t]), fmaxf(smax[2][t], smax[3][t])) + b2[t];
  }
}

extern "C" void kernel_launch(void* const* d_in, const int* in_sizes, int n_in,
                              void* d_out, int out_size, void* d_ws, size_t ws_size,
                              hipStream_t stream) {
  const float* x   = (const float*)d_in[0];
  const float* pos = (const float*)d_in[1];
  const float* sup = (const float*)d_in[2];
  const float* W1  = (const float*)d_in[3];
  const float* b1  = (const float*)d_in[4];
  const float* W2  = (const float*)d_in[5];
  const float* b2  = (const float*)d_in[6];
  const int* indices = (const int*)d_in[7];
  float* out = (float*)d_out;

  const size_t P2_BYTES  = (size_t)NPTS * 72 * 2;
  const size_t W1F_BYTES = 768 * 8 * 2;
  const size_t W2F_BYTES = 1024 * 8 * 2;
  if (ws_size >= P2_BYTES + W1F_BYTES + W2F_BYTES) {
    unsigned short* P2  = (unsigned short*)d_ws;
    unsigned short* W1F = (unsigned short*)((char*)d_ws + P2_BYTES);
    unsigned short* W2F = (unsigned short*)((char*)d_ws + P2_BYTES + W1F_BYTES);
    pack_all<<<NPTS/64, 256, 0, stream>>>(x, pos, W1, W2, P2, W1F, W2F);
    pointnet_mfma<<<MPTS/16, 256, 0, stream>>>(P2, sup, W1F, b1, W2F, b2, indices, out);
  } else {
    pointnet_fallback<<<MPTS, 256, 0, stream>>>(x, pos, sup, W1, b1, W2, b2, indices, out);
  }
}